// Round 9
// baseline (737.597 us; speedup 1.0000x reference)
//
#include <hip/hip_runtime.h>
#include <hip/hip_bf16.h>

#define EPS 1e-5f
typedef unsigned short bfr;   // raw bf16 bits
typedef unsigned short hfr;   // raw f16 bits
typedef _Float16 h2v __attribute__((ext_vector_type(2)));
typedef _Float16 f16x8 __attribute__((ext_vector_type(8)));
typedef float f32x4 __attribute__((ext_vector_type(4)));

#if defined(__has_builtin)
#if __has_builtin(__builtin_amdgcn_fdot2)
#define HAS_FDOT2 1
#endif
#endif

static inline int cdiv(int a, int b){ return (a + b - 1) / b; }
static inline int imin(int a, int b){ return a < b ? a : b; }

__device__ __forceinline__ float bf2f(bfr u){ return __uint_as_float((unsigned)u << 16); }
__device__ __forceinline__ bfr f2bf(float f){
  unsigned u = __float_as_uint(f);
  u += 0x7fffu + ((u >> 16) & 1u);
  return (bfr)(u >> 16);
}
__device__ __forceinline__ unsigned pack2bf(float a, float b){
  return (unsigned)f2bf(a) | ((unsigned)f2bf(b) << 16);
}
__device__ __forceinline__ float h2f(hfr u){ _Float16 h; __builtin_memcpy(&h, &u, 2); return (float)h; }
__device__ __forceinline__ hfr f2h(float f){ _Float16 h = (_Float16)f; hfr u; __builtin_memcpy(&u, &h, 2); return u; }
__device__ __forceinline__ unsigned pack2h(float a, float b){
  return (unsigned)f2h(a) | ((unsigned)f2h(b) << 16);
}
__device__ __forceinline__ h2v u2h2(unsigned u){ h2v r; __builtin_memcpy(&r, &u, 4); return r; }
__device__ __forceinline__ unsigned h22u(h2v h){ unsigned u; __builtin_memcpy(&u, &h, 4); return u; }
__device__ __forceinline__ float dot2(h2v a, h2v b, float c){
#ifdef HAS_FDOT2
  return __builtin_amdgcn_fdot2(a, b, c, false);
#else
  return c + (float)a.x * (float)b.x + (float)a.y * (float)b.y;
#endif
}

// ---------------- dtype detection (bf16 vs f32 inputs) ----------------
__global__ __launch_bounds__(256) void detect_kernel(const bfr* __restrict__ xr, int nwords, int* __restrict__ flag){
  int i = threadIdx.x;
  int bad = 0;
  if (i < nwords){
    bfr lo = xr[2 * i];
    int e = (lo >> 7) & 0xFF;
    bool plausible = ((lo & 0x7FFF) == 0) || (e >= 97 && e <= 157);
    bad = plausible ? 0 : 1;
  }
  __shared__ int s[256];
  s[threadIdx.x] = bad; __syncthreads();
  for (int st = 128; st; st >>= 1){
    if (threadIdx.x < st) s[threadIdx.x] += s[threadIdx.x + st];
    __syncthreads();
  }
  if (threadIdx.x == 0) *flag = (s[0] > 32) ? 1 : 0;
}

// ---------------- batched adaptive convert ----------------
#define NPAR 31
struct ParamPtrs { const void* p[NPAR]; };
struct ParamOfs  { int off[NPAR + 1]; };

__global__ __launch_bounds__(256) void acvt_batch_kernel(ParamPtrs pp, ParamOfs po,
                                                         float* __restrict__ out, int total,
                                                         const int* __restrict__ flag){
  int g = blockIdx.x * 256 + threadIdx.x;
  if (g >= total) return;
  int isf = *flag;
  int t = 0;
  while (po.off[t + 1] <= g) ++t;
  int i = g - po.off[t];
  out[g] = isf ? ((const float*)pp.p[t])[i] : bf2f(((const bfr*)pp.p[t])[i]);
}

// ---------------- counting sort of edges by dst (multi-block scan) ----------------
__global__ __launch_bounds__(256) void deg_kernel(const int* __restrict__ dst, int* __restrict__ deg, int E){
  int e = blockIdx.x * 256 + threadIdx.x;
  if (e < E) atomicAdd(&deg[dst[e]], 1);
}

__global__ __launch_bounds__(256) void scan1_kernel(const int* __restrict__ deg, int* __restrict__ locoff,
                                                    int* __restrict__ bsum, int N){
  __shared__ int s[256];
  int i = blockIdx.x * 256 + threadIdx.x;
  int v = (i < N) ? deg[i] : 0;
  s[threadIdx.x] = v; __syncthreads();
  for (int st = 1; st < 256; st <<= 1){
    int u = (threadIdx.x >= st) ? s[threadIdx.x - st] : 0;
    __syncthreads();
    s[threadIdx.x] += u;
    __syncthreads();
  }
  if (i < N) locoff[i] = s[threadIdx.x] - v;
  if (threadIdx.x == 255) bsum[blockIdx.x] = s[255];
}

// scan3 with self-computed carry (scan2 eliminated: each block reduces bsum[0..bid) itself)
__global__ __launch_bounds__(256) void scan3_kernel(const int* __restrict__ locoff, const int* __restrict__ bsum,
                                                    int* __restrict__ row_off, int* __restrict__ cur,
                                                    int N, int E){
  __shared__ int s[256];
  const int t = threadIdx.x;
  const int bid = blockIdx.x;
  int acc = 0;
  for (int base = 0; base < bid; base += 256){
    int idx = base + t;
    acc += (idx < bid) ? bsum[idx] : 0;
  }
  s[t] = acc; __syncthreads();
  for (int st = 128; st; st >>= 1){
    if (t < st) s[t] += s[t + st];
    __syncthreads();
  }
  const int carry = s[0];
  int i = bid * 256 + t;
  if (i < N){
    int v = locoff[i] + carry;
    row_off[i] = v; cur[i] = v;
  }
  if (i == 0) row_off[N] = E;
}

__global__ __launch_bounds__(256) void scatter_kernel(const int* __restrict__ src, const int* __restrict__ dst,
                                                      int* __restrict__ cur, int* __restrict__ ssrc, int E){
  int e = blockIdx.x * 256 + threadIdx.x;
  if (e < E){
    int d = dst[e];
    int p = atomicAdd(&cur[d], 1);
    ssrc[p] = src[e];
  }
}

// ---------------- first-layer fused P/Q GEMM (K=6, f32 A): y=0 -> P = A@(Wtop-Wbot)+ba ; y=1 -> Q = A@Wbot ----------------
template<bool FIRST>
__global__ __launch_bounds__(256) void gemmPQ_kernel(const void* __restrict__ Av, int lda,
                                                     const float* __restrict__ Wa, int d,
                                                     const float* __restrict__ ba,
                                                     hfr* __restrict__ P, hfr* __restrict__ Q, int N){
  __shared__ unsigned WsU[64 * 64];
  const int y = blockIdx.y;
  const int tot = d * 64;
  if (FIRST){
    float* Ws = (float*)WsU;
    for (int i = threadIdx.x; i < tot; i += 256)
      Ws[i] = y ? Wa[tot + i] : (Wa[i] - Wa[tot + i]);
  } else {
    for (int i = threadIdx.x; i < 32 * 64; i += 256){
      int p = i >> 6, c = i & 63;
      int i0 = (2 * p) * 64 + c, i1 = (2 * p + 1) * 64 + c;
      float w0 = y ? Wa[tot + i0] : (Wa[i0] - Wa[tot + i0]);
      float w1 = y ? Wa[tot + i1] : (Wa[i1] - Wa[tot + i1]);
      WsU[i] = pack2h(w0, w1);
    }
  }
  __syncthreads();
  const int row = blockIdx.x * 256 + threadIdx.x;
  if (row >= N) return;
  float acc[64];
#pragma unroll
  for (int c = 0; c < 64; ++c) acc[c] = 0.f;
  if (FIRST){
    const float* Ws = (const float*)WsU;
    const float* Af = (const float*)Av + (size_t)row * lda;
    for (int k = 0; k < d; ++k){
      float a = Af[k];
      const float* wr = Ws + k * 64;
#pragma unroll
      for (int c4 = 0; c4 < 16; ++c4){
        float4 w = *(const float4*)(wr + 4 * c4);
        acc[4*c4+0] += a * w.x; acc[4*c4+1] += a * w.y;
        acc[4*c4+2] += a * w.z; acc[4*c4+3] += a * w.w;
      }
    }
  } else {
    const hfr* Ah = (const hfr*)Av + (size_t)row * lda;
#pragma unroll
    for (int k8 = 0; k8 < 8; ++k8){
      uint4 av = *(const uint4*)(Ah + k8 * 8);
      unsigned pr[4] = {av.x, av.y, av.z, av.w};
#pragma unroll
      for (int pi = 0; pi < 4; ++pi){
        h2v ap = u2h2(pr[pi]);
        const unsigned* wr = WsU + (k8 * 4 + pi) * 64;
#pragma unroll
        for (int c = 0; c < 64; ++c) acc[c] = dot2(ap, u2h2(wr[c]), acc[c]);
      }
    }
  }
  if (!y){
#pragma unroll
    for (int c = 0; c < 64; ++c) acc[c] += ba[c];
  }
  unsigned p[32];
#pragma unroll
  for (int c = 0; c < 64; c += 2) p[c / 2] = pack2h(acc[c], acc[c + 1]);
  hfr* outp = (y ? Q : P) + (size_t)row * 64;
  uint4* op = (uint4*)outp;
#pragma unroll
  for (int i = 0; i < 8; ++i) op[i] = make_uint4(p[4*i], p[4*i+1], p[4*i+2], p[4*i+3]);
}

// ---------------- MFMA GEMM: C = relu?( A@W + bias ), BN-of-input fold, fused output BN stats, PQ2 mode ----
// Persistent blocks, 4 waves x 16 rows = 64-row tiles, NOUT-col tile per blockIdx.y.
// A[m=lane&15][k=(lane>>4)*8+j], B^T[n=lane&15][k], C[col=lane&15][row=(lane>>4)*4+r] (verified m120/m89).
// STATS: per-thread channel sum/sumsq accumulated during the tile loop, shfl+LDS reduced, one atomicAdd
// per channel per block. PQ2: NOUT=128 fused P/Q — cols 0-63 = A@(Wtop-Wbot)+ba -> Ov0, cols 64-127 =
// A@Wbot -> Ov1; A-fragments read ONCE feed 16 MFMAs (replaces the grid.y=2 double-read launch).
template<int NOUT, int KSTEPS, bool FOLD, bool PQ, bool STATS, bool PQ2>
__global__ __launch_bounds__(256) void mgemm_kernel(const hfr* __restrict__ Ah, int lda,
                                                    const float* __restrict__ Wp0, const float* __restrict__ Wm0, int ldw,
                                                    const float* __restrict__ bias0,
                                                    const float* __restrict__ stats, float cntInv,
                                                    const float* __restrict__ g, const float* __restrict__ be,
                                                    hfr* __restrict__ Ov0, hfr* __restrict__ Ov1, int ldo,
                                                    float* __restrict__ statsOut, int statC,
                                                    int nrows, int relu){
  constexpr int K  = KSTEPS * 32;
  constexpr int KP = K + 8;          // pad: keeps 16B alignment of frag reads, <=2-way bank alias
  constexpr int NT = NOUT / 16;
  __shared__ __align__(16) _Float16 W2T[NOUT * KP];         // [c][k] transposed (folded) weights
  __shared__ __align__(16) _Float16 etile[4][16][NOUT + 8]; // per-wave epilogue transpose tile
  __shared__ float aS[FOLD ? K : 1], bbS[FOLD ? K : 1], bsum[FOLD ? 256 : 1];
  __shared__ float bfull[NOUT];
  __shared__ float sred[STATS ? 4 * NOUT : 1], qred[STATS ? 4 * NOUT : 1];
  const int tid = threadIdx.x;
  const int lane = tid & 63;
  const int wib = tid >> 6;
  const float* Wp = Wp0;
  const float* Wm = Wm0;
  const float* bias = bias0;
  hfr* Ov = Ov0;
  int colbase = blockIdx.y * NOUT;
  if (PQ){
    colbase = 0;
    if (blockIdx.y == 1){ Wp = Wp0 + (size_t)K * ldw; Wm = nullptr; bias = nullptr; Ov = Ov1; }
    else { Wm = Wp0 + (size_t)K * ldw; }
  }
  if (PQ2) colbase = 0;

  if (FOLD){
    for (int k = tid; k < K; k += 256){
      float mu = stats[k] * cntInv;
      float var = stats[K + k] * cntInv - mu * mu;
      float ai = g[k] * rsqrtf(var + EPS);
      aS[k] = ai; bbS[k] = be[k] - ai * mu;
    }
    __syncthreads();
  }
  for (int i = tid; i < K * NOUT; i += 256){
    int k = i / NOUT, c = i - k * NOUT;
    float w;
    if (PQ2){
      w = (c < 64) ? (Wp[(size_t)k * ldw + c] - Wp[(size_t)(K + k) * ldw + c])
                   : Wp[(size_t)(K + k) * ldw + (c - 64)];
    } else {
      w = Wp[(size_t)k * ldw + colbase + c];
      if (Wm) w -= Wm[(size_t)k * ldw + colbase + c];
    }
    if (FOLD) w *= aS[k];
    W2T[c * KP + k] = (_Float16)w;
  }
  if (FOLD){
    constexpr int parts = 256 / NOUT;
    int c = tid % NOUT, p = tid / NOUT;
    float s = 0.f;
    for (int k = p; k < K; k += parts) s += bbS[k] * Wp[(size_t)k * ldw + colbase + c];
    bsum[p * NOUT + c] = s;
    __syncthreads();
    if (tid < NOUT){
      float t = bias[colbase + tid];
#pragma unroll
      for (int pp = 0; pp < parts; ++pp) t += bsum[pp * NOUT + tid];
      bfull[tid] = t;
    }
  } else {
    if (tid < NOUT){
      float bb = 0.f;
      if (bias && (!PQ2 || tid < 64)) bb = bias[colbase + tid];
      bfull[tid] = bb;
    }
  }
  __syncthreads();

  f16x8 Bf[KSTEPS][NT];
#pragma unroll
  for (int s = 0; s < KSTEPS; ++s)
#pragma unroll
    for (int t = 0; t < NT; ++t)
      Bf[s][t] = *(const f16x8*)&W2T[(t * 16 + (lane & 15)) * KP + s * 32 + (lane >> 4) * 8];
  float bc[NT];
#pragma unroll
  for (int t = 0; t < NT; ++t) bc[t] = bfull[t * 16 + (lane & 15)];

  float ssum[STATS ? NT : 1], qsum[STATS ? NT : 1];
  if (STATS){
#pragma unroll
    for (int t = 0; t < (STATS ? NT : 1); ++t){ ssum[t] = 0.f; qsum[t] = 0.f; }
  }
  const int lq2 = lane >> 4;

  const int ntiles = (nrows + 63) >> 6;
  for (int tile = blockIdx.x; tile < ntiles; tile += gridDim.x){
    const int r0 = tile * 64 + wib * 16;
    const int rowA = min(r0 + (lane & 15), nrows - 1);
    const hfr* Ap = Ah + (size_t)rowA * lda + (lane >> 4) * 8;
    f32x4 acc[NT];
#pragma unroll
    for (int t = 0; t < NT; ++t) acc[t] = (f32x4){bc[t], bc[t], bc[t], bc[t]};
#pragma unroll
    for (int s = 0; s < KSTEPS; ++s){
      f16x8 Af = *(const f16x8*)(Ap + s * 32);
#pragma unroll
      for (int t = 0; t < NT; ++t)
        acc[t] = __builtin_amdgcn_mfma_f32_16x16x32_f16(Af, Bf[s][t], acc[t], 0, 0, 0);
    }
    const bool fullTile = (r0 + 16 <= nrows);   // wave-uniform; only boundary tiles mask stats
#pragma unroll
    for (int t = 0; t < NT; ++t){
#pragma unroll
      for (int r = 0; r < 4; ++r){
        float v = acc[t][r];
        v = relu ? fmaxf(v, 0.f) : v;
        if (STATS){
          float vs = v;
          if (!fullTile) vs = ((r0 + lq2 * 4 + r) < nrows) ? vs : 0.f;
          ssum[t] += vs;
          qsum[t]  = fmaf(vs, vs, qsum[t]);
        }
        etile[wib][lq2 * 4 + r][t * 16 + (lane & 15)] = (_Float16)v;
      }
    }
    if (PQ2){
#pragma unroll
      for (int hh = 0; hh < 4; ++hh){
        int rl = hh * 4 + (lane >> 4);
        int ch16 = lane & 15;
        uint4 vv = *(const uint4*)&etile[wib][rl][ch16 * 8];
        int rg = r0 + rl;
        if (rg < nrows){
          hfr* bp = (ch16 < 8) ? Ov : Ov1;
          *(uint4*)(bp + (size_t)rg * ldo + (ch16 & 7) * 8) = vv;
        }
      }
    } else if (NOUT == 64){
#pragma unroll
      for (int h = 0; h < 2; ++h){
        int rl = h * 8 + (lane >> 3);
        int ch = lane & 7;
        uint4 vv = *(const uint4*)&etile[wib][rl][ch * 8];
        int rg = r0 + rl;
        if (rg < nrows) *(uint4*)(Ov + (size_t)rg * ldo + colbase + ch * 8) = vv;
      }
    } else {   // NOUT == 32
      int rl = lane >> 2;
      int ch = lane & 3;
      uint4 vv = *(const uint4*)&etile[wib][rl][ch * 8];
      int rg = r0 + rl;
      if (rg < nrows) *(uint4*)(Ov + (size_t)rg * ldo + colbase + ch * 8) = vv;
    }
  }

  if (STATS){
#pragma unroll
    for (int t = 0; t < NT; ++t){
      float s = ssum[t], q = qsum[t];
      s += __shfl_xor(s, 16, 64); s += __shfl_xor(s, 32, 64);
      q += __shfl_xor(q, 16, 64); q += __shfl_xor(q, 32, 64);
      if (lq2 == 0){ sred[wib * NOUT + t * 16 + lane] = s; qred[wib * NOUT + t * 16 + lane] = q; }
    }
    __syncthreads();
    if (tid < NOUT){
      float s = sred[tid] + sred[NOUT + tid] + sred[2 * NOUT + tid] + sred[3 * NOUT + tid];
      float q = qred[tid] + qred[NOUT + tid] + qred[2 * NOUT + tid] + qred[3 * NOUT + tid];
      atomicAdd(&statsOut[colbase + tid], s);
      atomicAdd(&statsOut[statC + colbase + tid], q);
    }
  }
}

// ---------------- passA: per-node P broadcast + Q fat-gather + relu -> h1 store + BN1 stats ----------------
// dst-sorted edges => each node owns contiguous rows [e0,e1) of h1. Lane: edge er0=lane>>3 (x2), chunk ck=lane&7.
__global__ __launch_bounds__(256) void passA_kernel(const hfr* __restrict__ P, const hfr* __restrict__ Q,
                                                    const int* __restrict__ ssrc, const int* __restrict__ row_off,
                                                    float* __restrict__ stats, hfr* __restrict__ h1, int N){
  const int tid = threadIdx.x;
  const int lane = tid & 63;
  const int wib = tid >> 6;
  const int er0 = lane >> 3;
  const int ck = lane & 7;
  const int wid = (blockIdx.x * 256 + tid) >> 6;
  const int nw = (gridDim.x * 256) >> 6;
  const _Float16 z16 = (_Float16)0;
  float s8[8], q8[8];
#pragma unroll
  for (int j = 0; j < 8; ++j){ s8[j] = 0.f; q8[j] = 0.f; }
  for (int n = wid; n < N; n += nw){
    const int e0 = row_off[n], e1 = row_off[n + 1];
    if (e0 >= e1) continue;
    uint4 pv4 = ((const uint4*)(P + (size_t)n * 64))[ck];
    h2v pp0 = u2h2(pv4.x), pp1 = u2h2(pv4.y), pp2 = u2h2(pv4.z), pp3 = u2h2(pv4.w);
    const int lim = e1 - 1;
    for (int eb = e0; eb < e1; eb += 16){
      int sv = ssrc[min(eb + (lane & 15), lim)];
#pragma unroll
      for (int h = 0; h < 2; ++h){
        int er = h * 8 + er0;
        int ge = eb + er;
        int sj = __shfl(sv, er, 64);
        uint4 qv = *((const uint4*)(Q + (size_t)sj * 64) + ck);
        h2v s0 = u2h2(qv.x) + pp0;
        h2v s1 = u2h2(qv.y) + pp1;
        h2v s2 = u2h2(qv.z) + pp2;
        h2v s3 = u2h2(qv.w) + pp3;
        s0.x = (s0.x < z16) ? z16 : s0.x; s0.y = (s0.y < z16) ? z16 : s0.y;
        s1.x = (s1.x < z16) ? z16 : s1.x; s1.y = (s1.y < z16) ? z16 : s1.y;
        s2.x = (s2.x < z16) ? z16 : s2.x; s2.y = (s2.y < z16) ? z16 : s2.y;
        s3.x = (s3.x < z16) ? z16 : s3.x; s3.y = (s3.y < z16) ? z16 : s3.y;
        if (ge < e1){
          *(uint4*)(h1 + (size_t)ge * 64 + ck * 8) = make_uint4(h22u(s0), h22u(s1), h22u(s2), h22u(s3));
          float v;
          v = (float)s0.x; s8[0] += v; q8[0] = fmaf(v, v, q8[0]);
          v = (float)s0.y; s8[1] += v; q8[1] = fmaf(v, v, q8[1]);
          v = (float)s1.x; s8[2] += v; q8[2] = fmaf(v, v, q8[2]);
          v = (float)s1.y; s8[3] += v; q8[3] = fmaf(v, v, q8[3]);
          v = (float)s2.x; s8[4] += v; q8[4] = fmaf(v, v, q8[4]);
          v = (float)s2.y; s8[5] += v; q8[5] = fmaf(v, v, q8[5]);
          v = (float)s3.x; s8[6] += v; q8[6] = fmaf(v, v, q8[6]);
          v = (float)s3.y; s8[7] += v; q8[7] = fmaf(v, v, q8[7]);
        }
      }
    }
  }
#pragma unroll
  for (int j = 0; j < 8; ++j){
    float s = s8[j], q = q8[j];
    s += __shfl_xor(s, 8, 64);  q += __shfl_xor(q, 8, 64);
    s += __shfl_xor(s, 16, 64); q += __shfl_xor(q, 16, 64);
    s += __shfl_xor(s, 32, 64); q += __shfl_xor(q, 32, 64);
    s8[j] = s; q8[j] = q;
  }
  __shared__ float ls[4][64], lq[4][64];
  if (lane < 8){
#pragma unroll
    for (int j = 0; j < 8; ++j){ ls[wib][lane * 8 + j] = s8[j]; lq[wib][lane * 8 + j] = q8[j]; }
  }
  __syncthreads();
  if (tid < 64){
    atomicAdd(&stats[tid], ls[0][tid] + ls[1][tid] + ls[2][tid] + ls[3][tid]);
  } else if (tid < 128){
    int c = tid - 64;
    atomicAdd(&stats[64 + c], lq[0][c] + lq[1][c] + lq[2][c] + lq[3][c]);
  }
}

// ---------------- passBC: read h1 directly as MFMA A-fragments (no gather, no LDS staging) ----------------
// A-frag: lane reads h1[(eb + (lane&15))*64 + (lane>>4)*8 .. +8] -- layout matches A[m][k] exactly.
__global__ __launch_bounds__(256) void passBC_kernel(const hfr* __restrict__ h1,
                                                     const int* __restrict__ row_off,
                                                     const float* __restrict__ statsIn, float Einv,
                                                     const float* __restrict__ g1, const float* __restrict__ be1,
                                                     const float* __restrict__ Wb, const float* __restrict__ bn,
                                                     float* __restrict__ agg, float* __restrict__ statsOut, int N){
  __shared__ __align__(16) _Float16 W2T[64 * 72];
  __shared__ float aS[64], bbS[64], b2S[64], bsum[256], qsum[256];
  const int tid = threadIdx.x;
  const int lane = tid & 63;
  if (tid < 64){
    float mu = statsIn[tid] * Einv;
    float var = statsIn[64 + tid] * Einv - mu * mu;
    float ai = g1[tid] * rsqrtf(var + EPS);
    aS[tid] = ai; bbS[tid] = be1[tid] - ai * mu;
  }
  __syncthreads();
  for (int i = tid; i < 4096; i += 256){
    int c = i >> 6, k = i & 63;
    W2T[c * 72 + k] = (_Float16)(aS[k] * Wb[(size_t)k * 64 + c]);
  }
  {
    int c = tid & 63, p = tid >> 6;   // parts = 4
    float s = 0.f;
    for (int k = p; k < 64; k += 4) s += bbS[k] * Wb[(size_t)k * 64 + c];
    bsum[p * 64 + c] = s;
  }
  __syncthreads();
  if (tid < 64) b2S[tid] = bn[tid] + bsum[tid] + bsum[64 + tid] + bsum[128 + tid] + bsum[192 + tid];
  __syncthreads();
  f16x8 Bf[4][2];
#pragma unroll
  for (int t = 0; t < 4; ++t)
#pragma unroll
    for (int h = 0; h < 2; ++h){
      int c = t * 16 + (lane & 15);
      Bf[t][h] = *(const f16x8*)&W2T[c * 72 + h * 32 + (lane >> 4) * 8];
    }
  float bc[4];
#pragma unroll
  for (int t = 0; t < 4; ++t) bc[t] = b2S[t * 16 + (lane & 15)];
  const int wid = (blockIdx.x * 256 + tid) >> 6;
  const int nw = (gridDim.x * 256) >> 6;
  float sumT[4] = {0.f,0.f,0.f,0.f}, sqT[4] = {0.f,0.f,0.f,0.f};
  for (int n = wid; n < N; n += nw){
    const int e0 = row_off[n], e1 = row_off[n + 1];
    if (e0 >= e1) continue;
    float mxT[4] = {0.f,0.f,0.f,0.f};
    for (int eb = e0; eb < e1; eb += 16){
      const hfr* ap = h1 + (size_t)(eb + (lane & 15)) * 64 + (lane >> 4) * 8;
      f16x8 A0 = *(const f16x8*)ap;
      f16x8 A1 = *(const f16x8*)(ap + 32);
#pragma unroll
      for (int t = 0; t < 4; ++t){
        f32x4 Cv = {bc[t], bc[t], bc[t], bc[t]};
        Cv = __builtin_amdgcn_mfma_f32_16x16x32_f16(A0, Bf[t][0], Cv, 0, 0, 0);
        Cv = __builtin_amdgcn_mfma_f32_16x16x32_f16(A1, Bf[t][1], Cv, 0, 0, 0);
#pragma unroll
        for (int r = 0; r < 4; ++r){
          int rowi = (lane >> 4) * 4 + r;
          float v = fmaxf(Cv[r], 0.f);
          v = ((eb + rowi) < e1) ? v : 0.f;      // rows past e1 belong to the next node
          mxT[t] = fmaxf(mxT[t], v);             // relu >= 0, so masked-0 is max-safe
          sumT[t] += v;
          sqT[t]  = fmaf(v, v, sqT[t]);
        }
      }
    }
#pragma unroll
    for (int t = 0; t < 4; ++t){
      float m = mxT[t];
      m = fmaxf(m, __shfl_xor(m, 16, 64));
      m = fmaxf(m, __shfl_xor(m, 32, 64));
      mxT[t] = m;
    }
    float outv = (lane < 16) ? mxT[0] : (lane < 32) ? mxT[1] : (lane < 48) ? mxT[2] : mxT[3];
    agg[(size_t)n * 64 + lane] = outv;
  }
#pragma unroll
  for (int t = 0; t < 4; ++t){
    float s = sumT[t], q = sqT[t];
    s += __shfl_xor(s, 16, 64); s += __shfl_xor(s, 32, 64);
    q += __shfl_xor(q, 16, 64); q += __shfl_xor(q, 32, 64);
    sumT[t] = s; sqT[t] = q;
  }
  float ssel = (lane < 16) ? sumT[0] : (lane < 32) ? sumT[1] : (lane < 48) ? sumT[2] : sumT[3];
  float qsel = (lane < 16) ? sqT[0]  : (lane < 32) ? sqT[1]  : (lane < 48) ? sqT[2]  : sqT[3];
  bsum[tid] = ssel; qsum[tid] = qsel;
  __syncthreads();
  if (tid < 64){
    atomicAdd(&statsOut[tid], bsum[tid] + bsum[64 + tid] + bsum[128 + tid] + bsum[192 + tid]);
  } else if (tid < 128){
    int c = tid - 64;
    atomicAdd(&statsOut[64 + c], qsum[c] + qsum[64 + c] + qsum[128 + c] + qsum[192 + c]);
  }
}

// ---------------- fixup with inlined BN2 coefficients (float4-vectorized, 4 ch/thread) ----------------
__global__ __launch_bounds__(256) void fixup_kernel(const float* __restrict__ agg, const int* __restrict__ deg,
                                                    const float* __restrict__ stats, float cntInv,
                                                    const float* __restrict__ g, const float* __restrict__ be,
                                                    hfr* __restrict__ xout, int ldx, int N){
  __shared__ float aC[64], bC[64];
  const int tid = threadIdx.x;
  if (tid < 64){
    float mu = stats[tid] * cntInv;
    float var = stats[64 + tid] * cntInv - mu * mu;
    float a = g[tid] * rsqrtf(var + EPS);
    aC[tid] = a; bC[tid] = be[tid] - a * mu;
  }
  __syncthreads();
  int t = blockIdx.x * 256 + tid;
  if (t >= N * 16) return;
  int n = t >> 4, c4 = (t & 15) * 4;
  float4 v4 = *(const float4*)(agg + (size_t)n * 64 + c4);
  bool live = deg[n] > 0;
  float o0 = live ? fmaf(v4.x, aC[c4 + 0], bC[c4 + 0]) : 0.f;
  float o1 = live ? fmaf(v4.y, aC[c4 + 1], bC[c4 + 1]) : 0.f;
  float o2 = live ? fmaf(v4.z, aC[c4 + 2], bC[c4 + 2]) : 0.f;
  float o3 = live ? fmaf(v4.w, aC[c4 + 3], bC[c4 + 3]) : 0.f;
  *(uint2*)(xout + (size_t)n * ldx + c4) = make_uint2(pack2h(o0, o1), pack2h(o2, o3));
}

// ---------------- head: inlined BN fold + logits + log_softmax ----------------
__global__ __launch_bounds__(256) void head_kernel(const hfr* __restrict__ u2,
                                                   const float* __restrict__ stats, float cntInv,
                                                   const float* __restrict__ g, const float* __restrict__ be,
                                                   const float* __restrict__ Wo, const float* __restrict__ bo,
                                                   void* __restrict__ out, int N, const int* __restrict__ flag){
  __shared__ float Ws[32 * 24];
  __shared__ float bs[24];
  __shared__ float aS[32], bbS[32];
  const int tid = threadIdx.x;
  if (tid < 32){
    float mu = stats[tid] * cntInv;
    float var = stats[32 + tid] * cntInv - mu * mu;
    float ai = g[tid] * rsqrtf(var + EPS);
    aS[tid] = ai; bbS[tid] = be[tid] - ai * mu;
  }
  __syncthreads();
  for (int i = tid; i < 32 * 24; i += 256){
    int k = i / 24, c = i - 24 * k;
    Ws[i] = aS[k] * Wo[(size_t)k * 24 + c];
  }
  if (tid < 24){
    float t = bo[tid];
    for (int k = 0; k < 32; ++k) t += bbS[k] * Wo[(size_t)k * 24 + tid];
    bs[tid] = t;
  }
  __syncthreads();
  int r = blockIdx.x * 256 + tid;
  if (r >= N) return;
  int isf = *flag;
  float l[24];
#pragma unroll
  for (int c = 0; c < 24; ++c) l[c] = bs[c];
  const hfr* up = u2 + (size_t)r * 32;
#pragma unroll
  for (int k = 0; k < 32; ++k){
    float v = h2f(up[k]);
#pragma unroll
    for (int c = 0; c < 24; ++c) l[c] += v * Ws[k * 24 + c];
  }
  float m = l[0];
#pragma unroll
  for (int c = 1; c < 24; ++c) m = fmaxf(m, l[c]);
  float s = 0.f;
#pragma unroll
  for (int c = 0; c < 24; ++c) s += expf(l[c] - m);
  float lse = m + logf(s);
  if (isf){
    float4* op = (float4*)((float*)out + (size_t)r * 24);
#pragma unroll
    for (int i = 0; i < 6; ++i)
      op[i] = make_float4(l[4*i] - lse, l[4*i+1] - lse, l[4*i+2] - lse, l[4*i+3] - lse);
  } else {
    unsigned p[12];
#pragma unroll
    for (int c = 0; c < 24; c += 2) p[c / 2] = pack2bf(l[c] - lse, l[c + 1] - lse);
    uint4* op = (uint4*)((bfr*)out + (size_t)r * 24);
#pragma unroll
    for (int i = 0; i < 3; ++i) op[i] = make_uint4(p[4*i], p[4*i+1], p[4*i+2], p[4*i+3]);
  }
}

// ---------------- host ----------------
// ROUND-25: round-8 base (723.5us) + three additive cuts:
//  (1) PQ2 fused mgemm for k=1,2: one NOUT=128 launch computes P (Wtop-Wbot,+ba)
//      and Q (Wbot) -- A-fragments read once feed 16 MFMAs (was 2 launches, A
//      read twice);
//  (2) scan2 eliminated (scan3 self-computes carry: removes a 1-block
//      serializing dispatch);
//  (3) fixup float4-vectorized with shared-staged BN coefficients.
extern "C" void kernel_launch(void* const* d_in, const int* in_sizes, int n_in,
                              void* d_out, int out_size, void* d_ws, size_t ws_size,
                              hipStream_t stream){
  const int N = in_sizes[0] / 6;
  const int E = in_sizes[31] / 2;
  const int* edge = (const int*)d_in[31];
  const int* src = edge;
  const int* dst = edge + E;

  size_t off = 0; char* basep = (char*)d_ws;
  auto alloc = [&](size_t bytes) -> void* {
    void* p = basep + off;
    off = (off + bytes + 255) & ~(size_t)255;
    return p;
  };
  float* stA  = (float*)alloc(1472 * 4);
  float* stN1 = stA + 768;
  float* stN2 = stA + 1280;
  float* stN3 = stA + 1408;
  int*   flag = (int*)  alloc(4);
  int*   deg  = (int*)  alloc((size_t)N * 4);
  int*   rowo = (int*)  alloc((size_t)(N + 1) * 4);
  int*   cur  = (int*)  alloc((size_t)N * 4);
  int*   loco = (int*)  alloc((size_t)N * 4);
  int*   bsc  = (int*)  alloc(1024 * 4);
  int*   ssrc = (int*)  alloc((size_t)E * 4);

  ParamPtrs pp; ParamOfs po;
  int hoff[32]; int total = 0;
  for (int s = 0; s < NPAR; ++s){
    int idx = (s < 30) ? (s + 1) : 0;
    pp.p[s] = d_in[idx];
    po.off[s] = total;
    hoff[idx] = total;
    total += in_sizes[idx];
  }
  po.off[NPAR] = total;
  float* pf = (float*)alloc((size_t)total * 4);

  hfr*   P    = (hfr*)  alloc((size_t)N * 64 * 2);
  hfr*   Qb   = (hfr*)  alloc((size_t)N * 64 * 2);
  float* agg  = (float*)alloc((size_t)N * 64 * 4);
  hfr*   xcat = (hfr*)  alloc((size_t)N * 192 * 2);
  hfr*   h1   = (hfr*)  alloc((size_t)(E + 16) * 64 * 2);
  hfr* u_l = (hfr*)P;                 // [N,256] f16 over P+Qb+agg
  hfr* u1  = xcat;                    // [N,64]  f16
  hfr* u2  = xcat + (size_t)N * 64;   // [N,32]  f16
  (void)ws_size; (void)n_in; (void)out_size;

  dim3 B(256);
  detect_kernel<<<1, B, 0, stream>>>((const bfr*)d_in[0], 256, flag);
  acvt_batch_kernel<<<cdiv(total, 256), B, 0, stream>>>(pp, po, pf, total, flag);

  hipMemsetAsync(stA, 0, 1472 * 4, stream);
  hipMemsetAsync(deg, 0, (size_t)N * 4, stream);
  hipMemsetAsync(h1 + (size_t)E * 64, 0, 16 * 64 * 2, stream);  // zero OOB tail tiles
  deg_kernel<<<cdiv(E, 256), B, 0, stream>>>(dst, deg, E);
  const int NBn = cdiv(N, 256);
  scan1_kernel<<<NBn, B, 0, stream>>>(deg, loco, bsc, N);
  scan3_kernel<<<NBn, B, 0, stream>>>(loco, bsc, rowo, cur, N, E);
  scatter_kernel<<<cdiv(E, 256), B, 0, stream>>>(src, dst, cur, ssrc, E);

  const int NB = cdiv(N, 256);
  const int ntiles = cdiv(N, 64);
  const int GWA = 1024, GWB = 1024;
  const float Einv = 1.f / (float)E;
  for (int k = 0; k < 3; ++k){
    const float *Wa_k, *ba_k, *ga_k, *bea_k, *Wb_k, *bb_k, *gb_k, *beb_k;
    if (k == 0){
      Wa_k = pf + hoff[1]; ba_k = pf + hoff[2]; ga_k = pf + hoff[3]; bea_k = pf + hoff[4];
      Wb_k = pf + hoff[5]; bb_k = pf + hoff[6]; gb_k = pf + hoff[7]; beb_k = pf + hoff[8];
    } else {
      int kk = k - 1;
      Wa_k = pf + hoff[9]  + (size_t)kk * 128 * 64;
      ba_k = pf + hoff[10] + kk * 64;
      ga_k = pf + hoff[11] + kk * 64;
      bea_k= pf + hoff[12] + kk * 64;
      Wb_k = pf + hoff[13] + (size_t)kk * 64 * 64;
      bb_k = pf + hoff[14] + kk * 64;
      gb_k = pf + hoff[15] + kk * 64;
      beb_k= pf + hoff[16] + kk * 64;
    }
    float* st1 = stA + k * 256;
    float* st2 = st1 + 128;
    if (k == 0){
      gemmPQ_kernel<true><<<dim3(NB, 2), B, 0, stream>>>(pf + hoff[0], 6, Wa_k, 6, ba_k, P, Qb, N);
    } else {
      // fused single-dispatch: cols 0-63 -> P = x@(Wtop-Wbot)+ba ; cols 64-127 -> Q = x@Wbot
      mgemm_kernel<128, 2, false, false, false, true><<<dim3(imin(ntiles, 1024), 1), B, 0, stream>>>(
          xcat + (size_t)(k - 1) * 64, 192, Wa_k, nullptr, 64, ba_k,
          nullptr, 0.f, nullptr, nullptr, P, Qb, 64, nullptr, 0, N, 0);
    }
    passA_kernel<<<GWA, B, 0, stream>>>(P, Qb, ssrc, rowo, st1, h1, N);
    passBC_kernel<<<GWB, B, 0, stream>>>(h1, rowo, st1, Einv, ga_k, bea_k, Wb_k, bb_k,
                                         agg, st2, N);
    fixup_kernel<<<cdiv(N * 16, 256), B, 0, stream>>>(agg, deg, st2, Einv, gb_k, beb_k,
                                                      xcat + (size_t)k * 64, 192, N);
  }

  // node MLP (BN folds inlined into consuming GEMMs / head; output stats fused into producers)
  mgemm_kernel<64, 6, false, false, true, false><<<dim3(imin(ntiles, 256), 4), B, 0, stream>>>(
      xcat, 192, pf + hoff[17], nullptr, 256, pf + hoff[18],
      nullptr, 0.f, nullptr, nullptr, u_l, nullptr, 256, stN1, 256, N, 1);
  mgemm_kernel<32, 8, true, false, true, false><<<dim3(imin(ntiles, 512), 2), B, 0, stream>>>(
      u_l, 256, pf + hoff[21], nullptr, 64, pf + hoff[22],
      stN1, 1.f / (float)N, pf + hoff[19], pf + hoff[20], u1, nullptr, 64, stN2, 64, N, 1);
  mgemm_kernel<32, 2, true, false, true, false><<<dim3(imin(ntiles, 1024), 1), B, 0, stream>>>(
      u1, 64, pf + hoff[25], nullptr, 32, pf + hoff[26],
      stN2, 1.f / (float)N, pf + hoff[23], pf + hoff[24], u2, nullptr, 32, stN3, 32, N, 1);
  head_kernel<<<cdiv(N, 256), B, 0, stream>>>(u2, stN3, 1.f / (float)N, pf + hoff[27], pf + hoff[28],
                                              pf + hoff[29], pf + hoff[30], d_out, N, flag);
  (void)NB;
}

// Round 10
// 711.281 us; speedup vs baseline: 1.0370x; 1.0370x over previous
//
#include <hip/hip_runtime.h>
#include <hip/hip_bf16.h>

#define EPS 1e-5f
typedef unsigned short bfr;   // raw bf16 bits
typedef unsigned short hfr;   // raw f16 bits
typedef _Float16 h2v __attribute__((ext_vector_type(2)));
typedef _Float16 f16x8 __attribute__((ext_vector_type(8)));
typedef float f32x4 __attribute__((ext_vector_type(4)));

#if defined(__has_builtin)
#if __has_builtin(__builtin_amdgcn_fdot2)
#define HAS_FDOT2 1
#endif
#endif

static inline int cdiv(int a, int b){ return (a + b - 1) / b; }
static inline int imin(int a, int b){ return a < b ? a : b; }

__device__ __forceinline__ float bf2f(bfr u){ return __uint_as_float((unsigned)u << 16); }
__device__ __forceinline__ bfr f2bf(float f){
  unsigned u = __float_as_uint(f);
  u += 0x7fffu + ((u >> 16) & 1u);
  return (bfr)(u >> 16);
}
__device__ __forceinline__ unsigned pack2bf(float a, float b){
  return (unsigned)f2bf(a) | ((unsigned)f2bf(b) << 16);
}
__device__ __forceinline__ float h2f(hfr u){ _Float16 h; __builtin_memcpy(&h, &u, 2); return (float)h; }
__device__ __forceinline__ hfr f2h(float f){ _Float16 h = (_Float16)f; hfr u; __builtin_memcpy(&u, &h, 2); return u; }
__device__ __forceinline__ unsigned pack2h(float a, float b){
  return (unsigned)f2h(a) | ((unsigned)f2h(b) << 16);
}
__device__ __forceinline__ h2v u2h2(unsigned u){ h2v r; __builtin_memcpy(&r, &u, 4); return r; }
__device__ __forceinline__ unsigned h22u(h2v h){ unsigned u; __builtin_memcpy(&u, &h, 4); return u; }
__device__ __forceinline__ float dot2(h2v a, h2v b, float c){
#ifdef HAS_FDOT2
  return __builtin_amdgcn_fdot2(a, b, c, false);
#else
  return c + (float)a.x * (float)b.x + (float)a.y * (float)b.y;
#endif
}

// ---------------- dtype detection (bf16 vs f32 inputs) ----------------
__global__ __launch_bounds__(256) void detect_kernel(const bfr* __restrict__ xr, int nwords, int* __restrict__ flag){
  int i = threadIdx.x;
  int bad = 0;
  if (i < nwords){
    bfr lo = xr[2 * i];
    int e = (lo >> 7) & 0xFF;
    bool plausible = ((lo & 0x7FFF) == 0) || (e >= 97 && e <= 157);
    bad = plausible ? 0 : 1;
  }
  __shared__ int s[256];
  s[threadIdx.x] = bad; __syncthreads();
  for (int st = 128; st; st >>= 1){
    if (threadIdx.x < st) s[threadIdx.x] += s[threadIdx.x + st];
    __syncthreads();
  }
  if (threadIdx.x == 0) *flag = (s[0] > 32) ? 1 : 0;
}

// ---------------- batched adaptive convert ----------------
#define NPAR 31
struct ParamPtrs { const void* p[NPAR]; };
struct ParamOfs  { int off[NPAR + 1]; };

__global__ __launch_bounds__(256) void acvt_batch_kernel(ParamPtrs pp, ParamOfs po,
                                                         float* __restrict__ out, int total,
                                                         const int* __restrict__ flag){
  int g = blockIdx.x * 256 + threadIdx.x;
  if (g >= total) return;
  int isf = *flag;
  int t = 0;
  while (po.off[t + 1] <= g) ++t;
  int i = g - po.off[t];
  out[g] = isf ? ((const float*)pp.p[t])[i] : bf2f(((const bfr*)pp.p[t])[i]);
}

// ---------------- counting sort of edges by dst (multi-block scan) ----------------
__global__ __launch_bounds__(256) void deg_kernel(const int* __restrict__ dst, int* __restrict__ deg, int E){
  int e = blockIdx.x * 256 + threadIdx.x;
  if (e < E) atomicAdd(&deg[dst[e]], 1);
}

__global__ __launch_bounds__(256) void scan1_kernel(const int* __restrict__ deg, int* __restrict__ locoff,
                                                    int* __restrict__ bsum, int N){
  __shared__ int s[256];
  int i = blockIdx.x * 256 + threadIdx.x;
  int v = (i < N) ? deg[i] : 0;
  s[threadIdx.x] = v; __syncthreads();
  for (int st = 1; st < 256; st <<= 1){
    int u = (threadIdx.x >= st) ? s[threadIdx.x - st] : 0;
    __syncthreads();
    s[threadIdx.x] += u;
    __syncthreads();
  }
  if (i < N) locoff[i] = s[threadIdx.x] - v;
  if (threadIdx.x == 255) bsum[blockIdx.x] = s[255];
}

// scan3 with self-computed carry (scan2 eliminated: each block reduces bsum[0..bid) itself)
__global__ __launch_bounds__(256) void scan3_kernel(const int* __restrict__ locoff, const int* __restrict__ bsum,
                                                    int* __restrict__ row_off, int* __restrict__ cur,
                                                    int N, int E){
  __shared__ int s[256];
  const int t = threadIdx.x;
  const int bid = blockIdx.x;
  int acc = 0;
  for (int base = 0; base < bid; base += 256){
    int idx = base + t;
    acc += (idx < bid) ? bsum[idx] : 0;
  }
  s[t] = acc; __syncthreads();
  for (int st = 128; st; st >>= 1){
    if (t < st) s[t] += s[t + st];
    __syncthreads();
  }
  const int carry = s[0];
  int i = bid * 256 + t;
  if (i < N){
    int v = locoff[i] + carry;
    row_off[i] = v; cur[i] = v;
  }
  if (i == 0) row_off[N] = E;
}

__global__ __launch_bounds__(256) void scatter_kernel(const int* __restrict__ src, const int* __restrict__ dst,
                                                      int* __restrict__ cur, int* __restrict__ ssrc, int E){
  int e = blockIdx.x * 256 + threadIdx.x;
  if (e < E){
    int d = dst[e];
    int p = atomicAdd(&cur[d], 1);
    ssrc[p] = src[e];
  }
}

// ---------------- first-layer fused P/Q GEMM (K=6, f32 A): y=0 -> P = A@(Wtop-Wbot)+ba ; y=1 -> Q = A@Wbot ----------------
template<bool FIRST>
__global__ __launch_bounds__(256) void gemmPQ_kernel(const void* __restrict__ Av, int lda,
                                                     const float* __restrict__ Wa, int d,
                                                     const float* __restrict__ ba,
                                                     hfr* __restrict__ P, hfr* __restrict__ Q, int N){
  __shared__ unsigned WsU[64 * 64];
  const int y = blockIdx.y;
  const int tot = d * 64;
  if (FIRST){
    float* Ws = (float*)WsU;
    for (int i = threadIdx.x; i < tot; i += 256)
      Ws[i] = y ? Wa[tot + i] : (Wa[i] - Wa[tot + i]);
  } else {
    for (int i = threadIdx.x; i < 32 * 64; i += 256){
      int p = i >> 6, c = i & 63;
      int i0 = (2 * p) * 64 + c, i1 = (2 * p + 1) * 64 + c;
      float w0 = y ? Wa[tot + i0] : (Wa[i0] - Wa[tot + i0]);
      float w1 = y ? Wa[tot + i1] : (Wa[i1] - Wa[tot + i1]);
      WsU[i] = pack2h(w0, w1);
    }
  }
  __syncthreads();
  const int row = blockIdx.x * 256 + threadIdx.x;
  if (row >= N) return;
  float acc[64];
#pragma unroll
  for (int c = 0; c < 64; ++c) acc[c] = 0.f;
  if (FIRST){
    const float* Ws = (const float*)WsU;
    const float* Af = (const float*)Av + (size_t)row * lda;
    for (int k = 0; k < d; ++k){
      float a = Af[k];
      const float* wr = Ws + k * 64;
#pragma unroll
      for (int c4 = 0; c4 < 16; ++c4){
        float4 w = *(const float4*)(wr + 4 * c4);
        acc[4*c4+0] += a * w.x; acc[4*c4+1] += a * w.y;
        acc[4*c4+2] += a * w.z; acc[4*c4+3] += a * w.w;
      }
    }
  } else {
    const hfr* Ah = (const hfr*)Av + (size_t)row * lda;
#pragma unroll
    for (int k8 = 0; k8 < 8; ++k8){
      uint4 av = *(const uint4*)(Ah + k8 * 8);
      unsigned pr[4] = {av.x, av.y, av.z, av.w};
#pragma unroll
      for (int pi = 0; pi < 4; ++pi){
        h2v ap = u2h2(pr[pi]);
        const unsigned* wr = WsU + (k8 * 4 + pi) * 64;
#pragma unroll
        for (int c = 0; c < 64; ++c) acc[c] = dot2(ap, u2h2(wr[c]), acc[c]);
      }
    }
  }
  if (!y){
#pragma unroll
    for (int c = 0; c < 64; ++c) acc[c] += ba[c];
  }
  unsigned p[32];
#pragma unroll
  for (int c = 0; c < 64; c += 2) p[c / 2] = pack2h(acc[c], acc[c + 1]);
  hfr* outp = (y ? Q : P) + (size_t)row * 64;
  uint4* op = (uint4*)outp;
#pragma unroll
  for (int i = 0; i < 8; ++i) op[i] = make_uint4(p[4*i], p[4*i+1], p[4*i+2], p[4*i+3]);
}

// ---------------- MFMA GEMM: C = relu?( A@W + bias ), optional BN-of-input fold, P/Q mode, fused output BN stats ----
// Persistent blocks, 4 waves x 16 rows = 64-row tiles, NOUT-col tile per blockIdx.y (or P/Q select in PQ mode).
// A[m=lane&15][k=(lane>>4)*8+j], B^T[n=lane&15][k], C[col=lane&15][row=(lane>>4)*4+r] (verified m120/m89).
// STATS: per-thread channel sum/sumsq of the (masked) outputs accumulated in registers during the tile loop,
// shfl+LDS reduced, one atomicAdd per channel per block -> replaces the separate statsN re-read pass.
template<int NOUT, int KSTEPS, bool FOLD, bool PQ, bool STATS>
__global__ __launch_bounds__(256) void mgemm_kernel(const hfr* __restrict__ Ah, int lda,
                                                    const float* __restrict__ Wp0, const float* __restrict__ Wm0, int ldw,
                                                    const float* __restrict__ bias0,
                                                    const float* __restrict__ stats, float cntInv,
                                                    const float* __restrict__ g, const float* __restrict__ be,
                                                    hfr* __restrict__ Ov0, hfr* __restrict__ Ov1, int ldo,
                                                    float* __restrict__ statsOut, int statC,
                                                    int nrows, int relu){
  constexpr int K  = KSTEPS * 32;
  constexpr int KP = K + 8;          // pad: keeps 16B alignment of frag reads, <=2-way bank alias
  constexpr int NT = NOUT / 16;
  __shared__ __align__(16) _Float16 W2T[NOUT * KP];         // [c][k] transposed (folded) weights
  __shared__ __align__(16) _Float16 etile[4][16][NOUT + 8]; // per-wave epilogue transpose tile
  __shared__ float aS[FOLD ? K : 1], bbS[FOLD ? K : 1], bsum[FOLD ? 256 : 1];
  __shared__ float bfull[NOUT];
  __shared__ float sred[STATS ? 4 * NOUT : 1], qred[STATS ? 4 * NOUT : 1];
  const int tid = threadIdx.x;
  const int lane = tid & 63;
  const int wib = tid >> 6;
  const float* Wp = Wp0;
  const float* Wm = Wm0;
  const float* bias = bias0;
  hfr* Ov = Ov0;
  int colbase = blockIdx.y * NOUT;
  if (PQ){
    colbase = 0;
    if (blockIdx.y == 1){ Wp = Wp0 + (size_t)K * ldw; Wm = nullptr; bias = nullptr; Ov = Ov1; }
    else { Wm = Wp0 + (size_t)K * ldw; }
  }

  if (FOLD){
    for (int k = tid; k < K; k += 256){
      float mu = stats[k] * cntInv;
      float var = stats[K + k] * cntInv - mu * mu;
      float ai = g[k] * rsqrtf(var + EPS);
      aS[k] = ai; bbS[k] = be[k] - ai * mu;
    }
    __syncthreads();
  }
  for (int i = tid; i < K * NOUT; i += 256){
    int k = i / NOUT, c = i - k * NOUT;
    float w = Wp[(size_t)k * ldw + colbase + c];
    if (Wm) w -= Wm[(size_t)k * ldw + colbase + c];
    if (FOLD) w *= aS[k];
    W2T[c * KP + k] = (_Float16)w;
  }
  if (FOLD){
    constexpr int parts = 256 / NOUT;
    int c = tid % NOUT, p = tid / NOUT;
    float s = 0.f;
    for (int k = p; k < K; k += parts) s += bbS[k] * Wp[(size_t)k * ldw + colbase + c];
    bsum[p * NOUT + c] = s;
    __syncthreads();
    if (tid < NOUT){
      float t = bias[colbase + tid];
#pragma unroll
      for (int pp = 0; pp < parts; ++pp) t += bsum[pp * NOUT + tid];
      bfull[tid] = t;
    }
  } else {
    if (tid < NOUT) bfull[tid] = bias ? bias[colbase + tid] : 0.f;
  }
  __syncthreads();

  f16x8 Bf[KSTEPS][NT];
#pragma unroll
  for (int s = 0; s < KSTEPS; ++s)
#pragma unroll
    for (int t = 0; t < NT; ++t)
      Bf[s][t] = *(const f16x8*)&W2T[(t * 16 + (lane & 15)) * KP + s * 32 + (lane >> 4) * 8];
  float bc[NT];
#pragma unroll
  for (int t = 0; t < NT; ++t) bc[t] = bfull[t * 16 + (lane & 15)];

  float ssum[STATS ? NT : 1], qsum[STATS ? NT : 1];
  if (STATS){
#pragma unroll
    for (int t = 0; t < (STATS ? NT : 1); ++t){ ssum[t] = 0.f; qsum[t] = 0.f; }
  }
  const int lq2 = lane >> 4;

  const int ntiles = (nrows + 63) >> 6;
  for (int tile = blockIdx.x; tile < ntiles; tile += gridDim.x){
    const int r0 = tile * 64 + wib * 16;
    const int rowA = min(r0 + (lane & 15), nrows - 1);
    const hfr* Ap = Ah + (size_t)rowA * lda + (lane >> 4) * 8;
    f32x4 acc[NT];
#pragma unroll
    for (int t = 0; t < NT; ++t) acc[t] = (f32x4){bc[t], bc[t], bc[t], bc[t]};
#pragma unroll
    for (int s = 0; s < KSTEPS; ++s){
      f16x8 Af = *(const f16x8*)(Ap + s * 32);
#pragma unroll
      for (int t = 0; t < NT; ++t)
        acc[t] = __builtin_amdgcn_mfma_f32_16x16x32_f16(Af, Bf[s][t], acc[t], 0, 0, 0);
    }
    const bool fullTile = (r0 + 16 <= nrows);   // wave-uniform; only boundary tiles mask stats
#pragma unroll
    for (int t = 0; t < NT; ++t){
#pragma unroll
      for (int r = 0; r < 4; ++r){
        float v = acc[t][r];
        v = relu ? fmaxf(v, 0.f) : v;
        if (STATS){
          float vs = v;
          if (!fullTile) vs = ((r0 + lq2 * 4 + r) < nrows) ? vs : 0.f;
          ssum[t] += vs;
          qsum[t]  = fmaf(vs, vs, qsum[t]);
        }
        etile[wib][lq2 * 4 + r][t * 16 + (lane & 15)] = (_Float16)v;
      }
    }
    if (NOUT == 64){
#pragma unroll
      for (int h = 0; h < 2; ++h){
        int rl = h * 8 + (lane >> 3);
        int ch = lane & 7;
        uint4 vv = *(const uint4*)&etile[wib][rl][ch * 8];
        int rg = r0 + rl;
        if (rg < nrows) *(uint4*)(Ov + (size_t)rg * ldo + colbase + ch * 8) = vv;
      }
    } else {   // NOUT == 32
      int rl = lane >> 2;
      int ch = lane & 3;
      uint4 vv = *(const uint4*)&etile[wib][rl][ch * 8];
      int rg = r0 + rl;
      if (rg < nrows) *(uint4*)(Ov + (size_t)rg * ldo + colbase + ch * 8) = vv;
    }
  }

  if (STATS){
#pragma unroll
    for (int t = 0; t < NT; ++t){
      float s = ssum[t], q = qsum[t];
      s += __shfl_xor(s, 16, 64); s += __shfl_xor(s, 32, 64);
      q += __shfl_xor(q, 16, 64); q += __shfl_xor(q, 32, 64);
      if (lq2 == 0){ sred[wib * NOUT + t * 16 + lane] = s; qred[wib * NOUT + t * 16 + lane] = q; }
    }
    __syncthreads();
    if (tid < NOUT){
      float s = sred[tid] + sred[NOUT + tid] + sred[2 * NOUT + tid] + sred[3 * NOUT + tid];
      float q = qred[tid] + qred[NOUT + tid] + qred[2 * NOUT + tid] + qred[3 * NOUT + tid];
      atomicAdd(&statsOut[colbase + tid], s);
      atomicAdd(&statsOut[statC + colbase + tid], q);
    }
  }
}

// ---------------- passA: per-node P broadcast + Q fat-gather + relu -> h1 store + BN1 stats ----------------
// dst-sorted edges => each node owns contiguous rows [e0,e1) of h1. Lane: edge er0=lane>>3 (x2), chunk ck=lane&7.
__global__ __launch_bounds__(256) void passA_kernel(const hfr* __restrict__ P, const hfr* __restrict__ Q,
                                                    const int* __restrict__ ssrc, const int* __restrict__ row_off,
                                                    float* __restrict__ stats, hfr* __restrict__ h1, int N){
  const int tid = threadIdx.x;
  const int lane = tid & 63;
  const int wib = tid >> 6;
  const int er0 = lane >> 3;
  const int ck = lane & 7;
  const int wid = (blockIdx.x * 256 + tid) >> 6;
  const int nw = (gridDim.x * 256) >> 6;
  const _Float16 z16 = (_Float16)0;
  float s8[8], q8[8];
#pragma unroll
  for (int j = 0; j < 8; ++j){ s8[j] = 0.f; q8[j] = 0.f; }
  for (int n = wid; n < N; n += nw){
    const int e0 = row_off[n], e1 = row_off[n + 1];
    if (e0 >= e1) continue;
    uint4 pv4 = ((const uint4*)(P + (size_t)n * 64))[ck];
    h2v pp0 = u2h2(pv4.x), pp1 = u2h2(pv4.y), pp2 = u2h2(pv4.z), pp3 = u2h2(pv4.w);
    const int lim = e1 - 1;
    for (int eb = e0; eb < e1; eb += 16){
      int sv = ssrc[min(eb + (lane & 15), lim)];
#pragma unroll
      for (int h = 0; h < 2; ++h){
        int er = h * 8 + er0;
        int ge = eb + er;
        int sj = __shfl(sv, er, 64);
        uint4 qv = *((const uint4*)(Q + (size_t)sj * 64) + ck);
        h2v s0 = u2h2(qv.x) + pp0;
        h2v s1 = u2h2(qv.y) + pp1;
        h2v s2 = u2h2(qv.z) + pp2;
        h2v s3 = u2h2(qv.w) + pp3;
        s0.x = (s0.x < z16) ? z16 : s0.x; s0.y = (s0.y < z16) ? z16 : s0.y;
        s1.x = (s1.x < z16) ? z16 : s1.x; s1.y = (s1.y < z16) ? z16 : s1.y;
        s2.x = (s2.x < z16) ? z16 : s2.x; s2.y = (s2.y < z16) ? z16 : s2.y;
        s3.x = (s3.x < z16) ? z16 : s3.x; s3.y = (s3.y < z16) ? z16 : s3.y;
        if (ge < e1){
          *(uint4*)(h1 + (size_t)ge * 64 + ck * 8) = make_uint4(h22u(s0), h22u(s1), h22u(s2), h22u(s3));
          float v;
          v = (float)s0.x; s8[0] += v; q8[0] = fmaf(v, v, q8[0]);
          v = (float)s0.y; s8[1] += v; q8[1] = fmaf(v, v, q8[1]);
          v = (float)s1.x; s8[2] += v; q8[2] = fmaf(v, v, q8[2]);
          v = (float)s1.y; s8[3] += v; q8[3] = fmaf(v, v, q8[3]);
          v = (float)s2.x; s8[4] += v; q8[4] = fmaf(v, v, q8[4]);
          v = (float)s2.y; s8[5] += v; q8[5] = fmaf(v, v, q8[5]);
          v = (float)s3.x; s8[6] += v; q8[6] = fmaf(v, v, q8[6]);
          v = (float)s3.y; s8[7] += v; q8[7] = fmaf(v, v, q8[7]);
        }
      }
    }
  }
#pragma unroll
  for (int j = 0; j < 8; ++j){
    float s = s8[j], q = q8[j];
    s += __shfl_xor(s, 8, 64);  q += __shfl_xor(q, 8, 64);
    s += __shfl_xor(s, 16, 64); q += __shfl_xor(q, 16, 64);
    s += __shfl_xor(s, 32, 64); q += __shfl_xor(q, 32, 64);
    s8[j] = s; q8[j] = q;
  }
  __shared__ float ls[4][64], lq[4][64];
  if (lane < 8){
#pragma unroll
    for (int j = 0; j < 8; ++j){ ls[wib][lane * 8 + j] = s8[j]; lq[wib][lane * 8 + j] = q8[j]; }
  }
  __syncthreads();
  if (tid < 64){
    atomicAdd(&stats[tid], ls[0][tid] + ls[1][tid] + ls[2][tid] + ls[3][tid]);
  } else if (tid < 128){
    int c = tid - 64;
    atomicAdd(&stats[64 + c], lq[0][c] + lq[1][c] + lq[2][c] + lq[3][c]);
  }
}

// ---------------- passBC: read h1 directly as MFMA A-fragments (no gather, no LDS staging) ----------------
// A-frag: lane reads h1[(eb + (lane&15))*64 + (lane>>4)*8 .. +8] -- layout matches A[m][k] exactly.
__global__ __launch_bounds__(256) void passBC_kernel(const hfr* __restrict__ h1,
                                                     const int* __restrict__ row_off,
                                                     const float* __restrict__ statsIn, float Einv,
                                                     const float* __restrict__ g1, const float* __restrict__ be1,
                                                     const float* __restrict__ Wb, const float* __restrict__ bn,
                                                     float* __restrict__ agg, float* __restrict__ statsOut, int N){
  __shared__ __align__(16) _Float16 W2T[64 * 72];
  __shared__ float aS[64], bbS[64], b2S[64], bsum[256], qsum[256];
  const int tid = threadIdx.x;
  const int lane = tid & 63;
  if (tid < 64){
    float mu = statsIn[tid] * Einv;
    float var = statsIn[64 + tid] * Einv - mu * mu;
    float ai = g1[tid] * rsqrtf(var + EPS);
    aS[tid] = ai; bbS[tid] = be1[tid] - ai * mu;
  }
  __syncthreads();
  for (int i = tid; i < 4096; i += 256){
    int c = i >> 6, k = i & 63;
    W2T[c * 72 + k] = (_Float16)(aS[k] * Wb[(size_t)k * 64 + c]);
  }
  {
    int c = tid & 63, p = tid >> 6;   // parts = 4
    float s = 0.f;
    for (int k = p; k < 64; k += 4) s += bbS[k] * Wb[(size_t)k * 64 + c];
    bsum[p * 64 + c] = s;
  }
  __syncthreads();
  if (tid < 64) b2S[tid] = bn[tid] + bsum[tid] + bsum[64 + tid] + bsum[128 + tid] + bsum[192 + tid];
  __syncthreads();
  f16x8 Bf[4][2];
#pragma unroll
  for (int t = 0; t < 4; ++t)
#pragma unroll
    for (int h = 0; h < 2; ++h){
      int c = t * 16 + (lane & 15);
      Bf[t][h] = *(const f16x8*)&W2T[c * 72 + h * 32 + (lane >> 4) * 8];
    }
  float bc[4];
#pragma unroll
  for (int t = 0; t < 4; ++t) bc[t] = b2S[t * 16 + (lane & 15)];
  const int wid = (blockIdx.x * 256 + tid) >> 6;
  const int nw = (gridDim.x * 256) >> 6;
  float sumT[4] = {0.f,0.f,0.f,0.f}, sqT[4] = {0.f,0.f,0.f,0.f};
  for (int n = wid; n < N; n += nw){
    const int e0 = row_off[n], e1 = row_off[n + 1];
    if (e0 >= e1) continue;
    float mxT[4] = {0.f,0.f,0.f,0.f};
    for (int eb = e0; eb < e1; eb += 16){
      const hfr* ap = h1 + (size_t)(eb + (lane & 15)) * 64 + (lane >> 4) * 8;
      f16x8 A0 = *(const f16x8*)ap;
      f16x8 A1 = *(const f16x8*)(ap + 32);
#pragma unroll
      for (int t = 0; t < 4; ++t){
        f32x4 Cv = {bc[t], bc[t], bc[t], bc[t]};
        Cv = __builtin_amdgcn_mfma_f32_16x16x32_f16(A0, Bf[t][0], Cv, 0, 0, 0);
        Cv = __builtin_amdgcn_mfma_f32_16x16x32_f16(A1, Bf[t][1], Cv, 0, 0, 0);
#pragma unroll
        for (int r = 0; r < 4; ++r){
          int rowi = (lane >> 4) * 4 + r;
          float v = fmaxf(Cv[r], 0.f);
          v = ((eb + rowi) < e1) ? v : 0.f;      // rows past e1 belong to the next node
          mxT[t] = fmaxf(mxT[t], v);             // relu >= 0, so masked-0 is max-safe
          sumT[t] += v;
          sqT[t]  = fmaf(v, v, sqT[t]);
        }
      }
    }
#pragma unroll
    for (int t = 0; t < 4; ++t){
      float m = mxT[t];
      m = fmaxf(m, __shfl_xor(m, 16, 64));
      m = fmaxf(m, __shfl_xor(m, 32, 64));
      mxT[t] = m;
    }
    float outv = (lane < 16) ? mxT[0] : (lane < 32) ? mxT[1] : (lane < 48) ? mxT[2] : mxT[3];
    agg[(size_t)n * 64 + lane] = outv;
  }
#pragma unroll
  for (int t = 0; t < 4; ++t){
    float s = sumT[t], q = sqT[t];
    s += __shfl_xor(s, 16, 64); s += __shfl_xor(s, 32, 64);
    q += __shfl_xor(q, 16, 64); q += __shfl_xor(q, 32, 64);
    sumT[t] = s; sqT[t] = q;
  }
  float ssel = (lane < 16) ? sumT[0] : (lane < 32) ? sumT[1] : (lane < 48) ? sumT[2] : sumT[3];
  float qsel = (lane < 16) ? sqT[0]  : (lane < 32) ? sqT[1]  : (lane < 48) ? sqT[2]  : sqT[3];
  bsum[tid] = ssel; qsum[tid] = qsel;
  __syncthreads();
  if (tid < 64){
    atomicAdd(&statsOut[tid], bsum[tid] + bsum[64 + tid] + bsum[128 + tid] + bsum[192 + tid]);
  } else if (tid < 128){
    int c = tid - 64;
    atomicAdd(&statsOut[64 + c], qsum[c] + qsum[64 + c] + qsum[128 + c] + qsum[192 + c]);
  }
}

// ---------------- fixup with inlined BN2 coefficients (float4-vectorized, 4 ch/thread) ----------------
__global__ __launch_bounds__(256) void fixup_kernel(const float* __restrict__ agg, const int* __restrict__ deg,
                                                    const float* __restrict__ stats, float cntInv,
                                                    const float* __restrict__ g, const float* __restrict__ be,
                                                    hfr* __restrict__ xout, int ldx, int N){
  __shared__ float aC[64], bC[64];
  const int tid = threadIdx.x;
  if (tid < 64){
    float mu = stats[tid] * cntInv;
    float var = stats[64 + tid] * cntInv - mu * mu;
    float a = g[tid] * rsqrtf(var + EPS);
    aC[tid] = a; bC[tid] = be[tid] - a * mu;
  }
  __syncthreads();
  int t = blockIdx.x * 256 + tid;
  if (t >= N * 16) return;
  int n = t >> 4, c4 = (t & 15) * 4;
  float4 v4 = *(const float4*)(agg + (size_t)n * 64 + c4);
  bool live = deg[n] > 0;
  float o0 = live ? fmaf(v4.x, aC[c4 + 0], bC[c4 + 0]) : 0.f;
  float o1 = live ? fmaf(v4.y, aC[c4 + 1], bC[c4 + 1]) : 0.f;
  float o2 = live ? fmaf(v4.z, aC[c4 + 2], bC[c4 + 2]) : 0.f;
  float o3 = live ? fmaf(v4.w, aC[c4 + 3], bC[c4 + 3]) : 0.f;
  *(uint2*)(xout + (size_t)n * ldx + c4) = make_uint2(pack2h(o0, o1), pack2h(o2, o3));
}

// ---------------- head: inlined BN fold + logits + log_softmax ----------------
__global__ __launch_bounds__(256) void head_kernel(const hfr* __restrict__ u2,
                                                   const float* __restrict__ stats, float cntInv,
                                                   const float* __restrict__ g, const float* __restrict__ be,
                                                   const float* __restrict__ Wo, const float* __restrict__ bo,
                                                   void* __restrict__ out, int N, const int* __restrict__ flag){
  __shared__ float Ws[32 * 24];
  __shared__ float bs[24];
  __shared__ float aS[32], bbS[32];
  const int tid = threadIdx.x;
  if (tid < 32){
    float mu = stats[tid] * cntInv;
    float var = stats[32 + tid] * cntInv - mu * mu;
    float ai = g[tid] * rsqrtf(var + EPS);
    aS[tid] = ai; bbS[tid] = be[tid] - ai * mu;
  }
  __syncthreads();
  for (int i = tid; i < 32 * 24; i += 256){
    int k = i / 24, c = i - 24 * k;
    Ws[i] = aS[k] * Wo[(size_t)k * 24 + c];
  }
  if (tid < 24){
    float t = bo[tid];
    for (int k = 0; k < 32; ++k) t += bbS[k] * Wo[(size_t)k * 24 + tid];
    bs[tid] = t;
  }
  __syncthreads();
  int r = blockIdx.x * 256 + tid;
  if (r >= N) return;
  int isf = *flag;
  float l[24];
#pragma unroll
  for (int c = 0; c < 24; ++c) l[c] = bs[c];
  const hfr* up = u2 + (size_t)r * 32;
#pragma unroll
  for (int k = 0; k < 32; ++k){
    float v = h2f(up[k]);
#pragma unroll
    for (int c = 0; c < 24; ++c) l[c] += v * Ws[k * 24 + c];
  }
  float m = l[0];
#pragma unroll
  for (int c = 1; c < 24; ++c) m = fmaxf(m, l[c]);
  float s = 0.f;
#pragma unroll
  for (int c = 0; c < 24; ++c) s += expf(l[c] - m);
  float lse = m + logf(s);
  if (isf){
    float4* op = (float4*)((float*)out + (size_t)r * 24);
#pragma unroll
    for (int i = 0; i < 6; ++i)
      op[i] = make_float4(l[4*i] - lse, l[4*i+1] - lse, l[4*i+2] - lse, l[4*i+3] - lse);
  } else {
    unsigned p[12];
#pragma unroll
    for (int c = 0; c < 24; c += 2) p[c / 2] = pack2bf(l[c] - lse, l[c + 1] - lse);
    uint4* op = (uint4*)((bfr*)out + (size_t)r * 24);
#pragma unroll
    for (int i = 0; i < 3; ++i) op[i] = make_uint4(p[4*i], p[4*i+1], p[4*i+2], p[4*i+3]);
  }
}

// ---------------- host ----------------
// ROUND-26: unbundle round-9. PQ2 (NOUT=128 fused P/Q) reverted -- its 36KB
// LDS + ~96 VGPR of fragments cost more residency than the A-re-read it saved
// (same ILP-vs-occupancy trap as rounds 3/4/5); back to round-8's grid.y=2
// NOUT=64 PQ launch, PQ2 code deleted. KEPT from round-9: scan2 elimination
// (scan3 self-computes carry) and float4-vectorized fixup -- the two safe cuts.
// Base config otherwise identical to round-8 (723.5us).
extern "C" void kernel_launch(void* const* d_in, const int* in_sizes, int n_in,
                              void* d_out, int out_size, void* d_ws, size_t ws_size,
                              hipStream_t stream){
  const int N = in_sizes[0] / 6;
  const int E = in_sizes[31] / 2;
  const int* edge = (const int*)d_in[31];
  const int* src = edge;
  const int* dst = edge + E;

  size_t off = 0; char* basep = (char*)d_ws;
  auto alloc = [&](size_t bytes) -> void* {
    void* p = basep + off;
    off = (off + bytes + 255) & ~(size_t)255;
    return p;
  };
  float* stA  = (float*)alloc(1472 * 4);
  float* stN1 = stA + 768;
  float* stN2 = stA + 1280;
  float* stN3 = stA + 1408;
  int*   flag = (int*)  alloc(4);
  int*   deg  = (int*)  alloc((size_t)N * 4);
  int*   rowo = (int*)  alloc((size_t)(N + 1) * 4);
  int*   cur  = (int*)  alloc((size_t)N * 4);
  int*   loco = (int*)  alloc((size_t)N * 4);
  int*   bsc  = (int*)  alloc(1024 * 4);
  int*   ssrc = (int*)  alloc((size_t)E * 4);

  ParamPtrs pp; ParamOfs po;
  int hoff[32]; int total = 0;
  for (int s = 0; s < NPAR; ++s){
    int idx = (s < 30) ? (s + 1) : 0;
    pp.p[s] = d_in[idx];
    po.off[s] = total;
    hoff[idx] = total;
    total += in_sizes[idx];
  }
  po.off[NPAR] = total;
  float* pf = (float*)alloc((size_t)total * 4);

  hfr*   P    = (hfr*)  alloc((size_t)N * 64 * 2);
  hfr*   Qb   = (hfr*)  alloc((size_t)N * 64 * 2);
  float* agg  = (float*)alloc((size_t)N * 64 * 4);
  hfr*   xcat = (hfr*)  alloc((size_t)N * 192 * 2);
  hfr*   h1   = (hfr*)  alloc((size_t)(E + 16) * 64 * 2);
  hfr* u_l = (hfr*)P;                 // [N,256] f16 over P+Qb+agg
  hfr* u1  = xcat;                    // [N,64]  f16
  hfr* u2  = xcat + (size_t)N * 64;   // [N,32]  f16
  (void)ws_size; (void)n_in; (void)out_size;

  dim3 B(256);
  detect_kernel<<<1, B, 0, stream>>>((const bfr*)d_in[0], 256, flag);
  acvt_batch_kernel<<<cdiv(total, 256), B, 0, stream>>>(pp, po, pf, total, flag);

  hipMemsetAsync(stA, 0, 1472 * 4, stream);
  hipMemsetAsync(deg, 0, (size_t)N * 4, stream);
  hipMemsetAsync(h1 + (size_t)E * 64, 0, 16 * 64 * 2, stream);  // zero OOB tail tiles
  deg_kernel<<<cdiv(E, 256), B, 0, stream>>>(dst, deg, E);
  const int NBn = cdiv(N, 256);
  scan1_kernel<<<NBn, B, 0, stream>>>(deg, loco, bsc, N);
  scan3_kernel<<<NBn, B, 0, stream>>>(loco, bsc, rowo, cur, N, E);
  scatter_kernel<<<cdiv(E, 256), B, 0, stream>>>(src, dst, cur, ssrc, E);

  const int NB = cdiv(N, 256);
  const int ntiles = cdiv(N, 64);
  const int GWA = 1024, GWB = 1024;
  const float Einv = 1.f / (float)E;
  for (int k = 0; k < 3; ++k){
    const float *Wa_k, *ba_k, *ga_k, *bea_k, *Wb_k, *bb_k, *gb_k, *beb_k;
    if (k == 0){
      Wa_k = pf + hoff[1]; ba_k = pf + hoff[2]; ga_k = pf + hoff[3]; bea_k = pf + hoff[4];
      Wb_k = pf + hoff[5]; bb_k = pf + hoff[6]; gb_k = pf + hoff[7]; beb_k = pf + hoff[8];
    } else {
      int kk = k - 1;
      Wa_k = pf + hoff[9]  + (size_t)kk * 128 * 64;
      ba_k = pf + hoff[10] + kk * 64;
      ga_k = pf + hoff[11] + kk * 64;
      bea_k= pf + hoff[12] + kk * 64;
      Wb_k = pf + hoff[13] + (size_t)kk * 64 * 64;
      bb_k = pf + hoff[14] + kk * 64;
      gb_k = pf + hoff[15] + kk * 64;
      beb_k= pf + hoff[16] + kk * 64;
    }
    float* st1 = stA + k * 256;
    float* st2 = st1 + 128;
    if (k == 0){
      gemmPQ_kernel<true><<<dim3(NB, 2), B, 0, stream>>>(pf + hoff[0], 6, Wa_k, 6, ba_k, P, Qb, N);
    } else {
      // fused: y=0 -> P = x@(Wtop-Wbot)+ba ; y=1 -> Q = x@Wbot
      mgemm_kernel<64, 2, false, true, false><<<dim3(imin(ntiles, 1024), 2), B, 0, stream>>>(
          xcat + (size_t)(k - 1) * 64, 192, Wa_k, nullptr, 64, ba_k,
          nullptr, 0.f, nullptr, nullptr, P, Qb, 64, nullptr, 0, N, 0);
    }
    passA_kernel<<<GWA, B, 0, stream>>>(P, Qb, ssrc, rowo, st1, h1, N);
    passBC_kernel<<<GWB, B, 0, stream>>>(h1, rowo, st1, Einv, ga_k, bea_k, Wb_k, bb_k,
                                         agg, st2, N);
    fixup_kernel<<<cdiv(N * 16, 256), B, 0, stream>>>(agg, deg, st2, Einv, gb_k, beb_k,
                                                      xcat + (size_t)k * 64, 192, N);
  }

  // node MLP (BN folds inlined into consuming GEMMs / head; output stats fused into producers)
  mgemm_kernel<64, 6, false, false, true><<<dim3(imin(ntiles, 256), 4), B, 0, stream>>>(
      xcat, 192, pf + hoff[17], nullptr, 256, pf + hoff[18],
      nullptr, 0.f, nullptr, nullptr, u_l, nullptr, 256, stN1, 256, N, 1);
  mgemm_kernel<32, 8, true, false, true><<<dim3(imin(ntiles, 512), 2), B, 0, stream>>>(
      u_l, 256, pf + hoff[21], nullptr, 64, pf + hoff[22],
      stN1, 1.f / (float)N, pf + hoff[19], pf + hoff[20], u1, nullptr, 64, stN2, 64, N, 1);
  mgemm_kernel<32, 2, true, false, true><<<dim3(imin(ntiles, 1024), 1), B, 0, stream>>>(
      u1, 64, pf + hoff[25], nullptr, 32, pf + hoff[26],
      stN2, 1.f / (float)N, pf + hoff[23], pf + hoff[24], u2, nullptr, 32, stN3, 32, N, 1);
  head_kernel<<<cdiv(N, 256), B, 0, stream>>>(u2, stN3, 1.f / (float)N, pf + hoff[27], pf + hoff[28],
                                              pf + hoff[29], pf + hoff[30], d_out, N, flag);
  (void)NB;
}